// Round 1
// baseline (491.318 us; speedup 1.0000x reference)
//
#include <hip/hip_runtime.h>

typedef unsigned short u16;
typedef unsigned int u32;

typedef __attribute__((ext_vector_type(8))) short short8;
typedef __attribute__((ext_vector_type(4))) float floatx4;

__device__ __forceinline__ float bf2f(u16 u) { return __uint_as_float(((u32)u) << 16); }
__device__ __forceinline__ u16 f2bf(float f) {
    u32 x = __float_as_uint(f);
    x += 0x7fffu + ((x >> 16) & 1u);
    return (u16)(x >> 16);
}
__device__ __forceinline__ void gl_lds16(const void* g, void* l) {
    __builtin_amdgcn_global_load_lds((const __attribute__((address_space(1))) u32*)g,
                                     (__attribute__((address_space(3))) u32*)l, 16, 0, 0);
}

// ---------------- Kernel 1: x (B,C,D,H,W) -> t (B,HW,DIM) bf16, + pos ----------------
__global__ __launch_bounds__(256) void k_tpos(const float* __restrict__ x,
                                              const float* __restrict__ pos,
                                              u16* __restrict__ t) {
    __shared__ float tile[64][65];
    const int b = blockIdx.z, hw0 = blockIdx.y * 64, cd0 = blockIdx.x * 64;
    const int tid = threadIdx.x;
#pragma unroll
    for (int i = 0; i < 16; i++) {
        int f = i * 256 + tid;
        int cdl = f >> 6, hwl = f & 63;
        int cd = cd0 + cdl, c = cd >> 3, d = cd & 7;
        tile[cdl][hwl] = x[(size_t)(((b * 96 + c) * 8 + d)) * 1024 + hw0 + hwl];
    }
    __syncthreads();
#pragma unroll
    for (int i = 0; i < 16; i++) {
        int f = i * 256 + tid;
        int hwl = f >> 6, cdl = f & 63;
        float v = tile[cdl][hwl] + pos[(size_t)(hw0 + hwl) * 768 + cd0 + cdl];
        t[(size_t)(b * 1024 + hw0 + hwl) * 768 + cd0 + cdl] = f2bf(v);
    }
}

// ---------------- weight fp32 -> bf16 (qkv_w then proj_w concatenated) ----------------
__global__ __launch_bounds__(256) void k_cvt(const float* __restrict__ wq,
                                             const float* __restrict__ wp,
                                             u16* __restrict__ out) {
    int i = blockIdx.x * 256 + threadIdx.x;
    const int NQ = 2304 * 768;
    float v = (i < NQ) ? wq[i] : wp[i - NQ];
    out[i] = f2bf(v);
}

// ---------------- GEMM: C(M,N) = A(M,K) * Bw(N,K)^T, bf16 MFMA ----------------
// MODE 0: QKV epilogue -> q,k [b,h,n,dh] and v transposed [b,h,dh,n]
// MODE 1: proj epilogue -> Co fp32 row-major + bias
template <int MODE>
__global__ __launch_bounds__(256) void gemm_bt(const u16* __restrict__ A,
                                               const u16* __restrict__ Bw,
                                               int M, int N, int K,
                                               u16* __restrict__ qo, u16* __restrict__ ko,
                                               u16* __restrict__ vo,
                                               const float* __restrict__ bias,
                                               float* __restrict__ Co) {
    __shared__ __align__(16) u16 lA[128 * 32];
    __shared__ __align__(16) u16 lB[128 * 32];
    const int tid = threadIdx.x;
    const int lane = tid & 63;
    const int wv = tid >> 6;
    const int wr = wv >> 1, wc = wv & 1;
    const int ntiles = N >> 7;
    const int m0 = (blockIdx.x / ntiles) << 7;
    const int n0 = (blockIdx.x % ntiles) << 7;
    const int lr = lane & 15;
    const int lq = lane >> 4;
    const int koff = lq * 8;

    floatx4 acc[4][4];
#pragma unroll
    for (int i = 0; i < 4; i++)
#pragma unroll
        for (int j = 0; j < 4; j++) acc[i][j] = (floatx4){0.f, 0.f, 0.f, 0.f};

    for (int kt = 0; kt < K; kt += 32) {
        __syncthreads();
#pragma unroll
        for (int i = 0; i < 2; i++) {
            int ch = i * 256 + tid;
            int row = ch >> 2, kc = ch & 3;
            const u16* ga = A + (size_t)(m0 + row) * K + kt + kc * 8;
            gl_lds16(ga, (char*)lA + (i * 256 + (tid & ~63)) * 16);
            const u16* gb = Bw + (size_t)(n0 + row) * K + kt + kc * 8;
            gl_lds16(gb, (char*)lB + (i * 256 + (tid & ~63)) * 16);
        }
        __syncthreads();
        short8 af[4], bfr[4];
#pragma unroll
        for (int tt = 0; tt < 4; tt++) {
            af[tt] = *(const short8*)(lA + (wr * 64 + tt * 16 + lr) * 32 + koff);
            bfr[tt] = *(const short8*)(lB + (wc * 64 + tt * 16 + lr) * 32 + koff);
        }
#pragma unroll
        for (int mt = 0; mt < 4; mt++)
#pragma unroll
            for (int nt = 0; nt < 4; nt++)
                acc[mt][nt] = __builtin_amdgcn_mfma_f32_16x16x32_bf16(af[mt], bfr[nt], acc[mt][nt], 0, 0, 0);
    }

    if (MODE == 0) {
#pragma unroll
        for (int nt = 0; nt < 4; nt++) {
            int col = n0 + wc * 64 + nt * 16 + lr;
            int three = col / 768;
            int rem = col - three * 768;
            int h = rem / 192;
            int dh = rem - h * 192;
#pragma unroll
            for (int mt = 0; mt < 4; mt++) {
#pragma unroll
                for (int r = 0; r < 4; r++) {
                    int row = m0 + wr * 64 + mt * 16 + lq * 4 + r;
                    int b = row >> 10, n = row & 1023;
                    u16 val = f2bf(acc[mt][nt][r]);
                    size_t bh = (size_t)(b * 4 + h);
                    if (three == 0)
                        qo[(bh * 1024 + n) * 192 + dh] = val;
                    else if (three == 1)
                        ko[(bh * 1024 + n) * 192 + dh] = val;
                    else
                        vo[(bh * 192 + dh) * 1024 + n] = val;
                }
            }
        }
    } else {
#pragma unroll
        for (int nt = 0; nt < 4; nt++) {
            int col = n0 + wc * 64 + nt * 16 + lr;
            float bv = bias[col];
#pragma unroll
            for (int mt = 0; mt < 4; mt++) {
#pragma unroll
                for (int r = 0; r < 4; r++) {
                    int row = m0 + wr * 64 + mt * 16 + lq * 4 + r;
                    Co[(size_t)row * N + col] = acc[mt][nt][r] + bv;
                }
            }
        }
    }
}

// ---------------- column sum-of-squares over sequence (for l2norm over dim=-2) ----------------
__global__ void k_sq(const u16* __restrict__ q, const u16* __restrict__ k,
                     float* __restrict__ sqq, float* __restrict__ sqk) {
    int bh = blockIdx.x;
    int part = blockIdx.y;
    int dh = threadIdx.x;  // 192
    const u16* qp = q + ((size_t)bh * 1024 + part * 128) * 192 + dh;
    const u16* kp = k + ((size_t)bh * 1024 + part * 128) * 192 + dh;
    float aq = 0.f, ak = 0.f;
#pragma unroll 4
    for (int n = 0; n < 128; n++) {
        float a = bf2f(qp[(size_t)n * 192]);
        aq += a * a;
        float c2 = bf2f(kp[(size_t)n * 192]);
        ak += c2 * c2;
    }
    atomicAdd(&sqq[bh * 192 + dh], aq);
    atomicAdd(&sqk[bh * 192 + dh], ak);
}

__global__ void k_scale(const float* __restrict__ sqq, const float* __restrict__ sqk,
                        const float* __restrict__ temp, float* __restrict__ cs) {
    int bh = blockIdx.x;
    int dh = threadIdx.x;
    float rq = 1.f / fmaxf(sqrtf(sqq[bh * 192 + dh]), 1e-12f);
    float rk = 1.f / fmaxf(sqrtf(sqk[bh * 192 + dh]), 1e-12f);
    cs[bh * 192 + dh] = rq * rk * temp[bh & 3];
}

// ---------------- flash attention: one WG per (bh, 64-row q block) ----------------
__global__ __launch_bounds__(256) void k_attn(const u16* __restrict__ q,
                                              const u16* __restrict__ kmat,
                                              const u16* __restrict__ vT,
                                              const float* __restrict__ cs,
                                              u16* __restrict__ o) {
    __shared__ __align__(16) u16 lK[64 * 192];   // 24KB [krow][dh]
    __shared__ __align__(16) u16 lV[192 * 64];   // 24KB [dh][krow]
    __shared__ __align__(16) u16 lP[4 * 16 * 64];  // 8KB per-wave [qrow][krow]
    const int qb = blockIdx.x;
    const int bh = blockIdx.y;
    const int b = bh >> 2, h = bh & 3;
    const int tid = threadIdx.x;
    const int lane = tid & 63;
    const int wv = tid >> 6;
    const int lr = lane & 15;
    const int lq = lane >> 4;
    const int koff = lq * 8;

    const u16* qbase = q + (size_t)bh * 1024 * 192;
    const u16* kbase = kmat + (size_t)bh * 1024 * 192;
    const u16* vbase = vT + (size_t)bh * 192 * 1024;
    const float* cp = cs + bh * 192;

    // Q fragments in registers, scaled by combined norm/temperature factor
    const int qrow = qb * 64 + wv * 16 + lr;
    const u16* qp = qbase + (size_t)qrow * 192;
    short8 qf[6];
#pragma unroll
    for (int ks = 0; ks < 6; ks++) {
        short8 raw = *(const short8*)(qp + ks * 32 + koff);
        short8 sc;
#pragma unroll
        for (int j = 0; j < 8; j++) {
            float f = bf2f((u16)raw[j]) * cp[ks * 32 + koff + j];
            sc[j] = (short)f2bf(f);
        }
        qf[ks] = sc;
    }

    float m_r[4], l_r[4];
    floatx4 oacc[12];
#pragma unroll
    for (int r = 0; r < 4; r++) { m_r[r] = -1e30f; l_r[r] = 0.f; }
#pragma unroll
    for (int vt = 0; vt < 12; vt++) oacc[vt] = (floatx4){0.f, 0.f, 0.f, 0.f};

    for (int kb = 0; kb < 16; kb++) {
        __syncthreads();
        // stage K block [64][192] and V^T block [192][64]
#pragma unroll
        for (int i = 0; i < 6; i++) {
            int ch = i * 256 + tid;
            int r = ch / 24, cc = ch - r * 24;
            const u16* gk = kbase + (size_t)(kb * 64 + r) * 192 + cc * 8;
            gl_lds16(gk, (char*)lK + (i * 256 + (tid & ~63)) * 16);
            int dh2 = ch >> 3, c2 = ch & 7;
            const u16* gv = vbase + (size_t)dh2 * 1024 + kb * 64 + c2 * 8;
            gl_lds16(gv, (char*)lV + (i * 256 + (tid & ~63)) * 16);
        }
        __syncthreads();

        // S = Qs * K^T : 4 n-tiles of 16
        floatx4 s[4];
#pragma unroll
        for (int nt = 0; nt < 4; nt++) s[nt] = (floatx4){0.f, 0.f, 0.f, 0.f};
#pragma unroll
        for (int ks = 0; ks < 6; ks++) {
#pragma unroll
            for (int nt = 0; nt < 4; nt++) {
                short8 kf = *(const short8*)(lK + (nt * 16 + lr) * 192 + ks * 32 + koff);
                s[nt] = __builtin_amdgcn_mfma_f32_16x16x32_bf16(qf[ks], kf, s[nt], 0, 0, 0);
            }
        }

        // online softmax (rows = lq*4 + r, consistent across the 16 lanes of each quad)
        float rmax[4];
#pragma unroll
        for (int r = 0; r < 4; r++)
            rmax[r] = fmaxf(fmaxf(s[0][r], s[1][r]), fmaxf(s[2][r], s[3][r]));
#pragma unroll
        for (int m = 1; m < 16; m <<= 1)
#pragma unroll
            for (int r = 0; r < 4; r++) rmax[r] = fmaxf(rmax[r], __shfl_xor(rmax[r], m));
        float alpha[4];
#pragma unroll
        for (int r = 0; r < 4; r++) {
            float mn = fmaxf(m_r[r], rmax[r]);
            alpha[r] = __expf(m_r[r] - mn);
            m_r[r] = mn;
        }
        float rsum[4] = {0.f, 0.f, 0.f, 0.f};
#pragma unroll
        for (int nt = 0; nt < 4; nt++)
#pragma unroll
            for (int r = 0; r < 4; r++) {
                float p = __expf(s[nt][r] - m_r[r]);
                s[nt][r] = p;
                rsum[r] += p;
            }
#pragma unroll
        for (int m = 1; m < 16; m <<= 1)
#pragma unroll
            for (int r = 0; r < 4; r++) rsum[r] += __shfl_xor(rsum[r], m);
#pragma unroll
        for (int r = 0; r < 4; r++) l_r[r] = l_r[r] * alpha[r] + rsum[r];
#pragma unroll
        for (int vt = 0; vt < 12; vt++)
#pragma unroll
            for (int r = 0; r < 4; r++) oacc[vt][r] *= alpha[r];

        // P -> per-wave LDS (C-layout -> A-layout transform)
        u16* lp = lP + wv * (16 * 64);
#pragma unroll
        for (int nt = 0; nt < 4; nt++)
#pragma unroll
            for (int r = 0; r < 4; r++)
                lp[(lq * 4 + r) * 64 + nt * 16 + lr] = f2bf(s[nt][r]);

        // O += P * V
#pragma unroll
        for (int ks2 = 0; ks2 < 2; ks2++) {
            short8 pf = *(const short8*)(lp + lr * 64 + ks2 * 32 + koff);
#pragma unroll
            for (int vt = 0; vt < 12; vt++) {
                short8 vf = *(const short8*)(lV + (vt * 16 + lr) * 64 + ks2 * 32 + koff);
                oacc[vt] = __builtin_amdgcn_mfma_f32_16x16x32_bf16(pf, vf, oacc[vt], 0, 0, 0);
            }
        }
    }

    // epilogue: divide by l, write to o (B,HW,DIM) bf16
    float inv[4];
#pragma unroll
    for (int r = 0; r < 4; r++) inv[r] = 1.f / l_r[r];
#pragma unroll
    for (int vt = 0; vt < 12; vt++) {
        int dh = vt * 16 + lr;
#pragma unroll
        for (int r = 0; r < 4; r++) {
            int row = qb * 64 + wv * 16 + lq * 4 + r;
            o[(size_t)(b * 1024 + row) * 768 + h * 192 + dh] = f2bf(oacc[vt][r] * inv[r]);
        }
    }
}

// ---------------- LN stats per row ----------------
__global__ __launch_bounds__(256) void k_lnstats(const float* __restrict__ o2,
                                                 float* __restrict__ mu,
                                                 float* __restrict__ rstd) {
    int row = blockIdx.x;
    int tid = threadIdx.x;
    const float* p = o2 + (size_t)row * 768;
    float s = 0.f, ss = 0.f;
    for (int i = tid; i < 768; i += 256) {
        float v = p[i];
        s += v;
        ss += v * v;
    }
#pragma unroll
    for (int m = 32; m >= 1; m >>= 1) {
        s += __shfl_xor(s, m);
        ss += __shfl_xor(ss, m);
    }
    __shared__ float as[4], ass[4];
    if ((tid & 63) == 0) {
        as[tid >> 6] = s;
        ass[tid >> 6] = ss;
    }
    __syncthreads();
    if (tid == 0) {
        float S = as[0] + as[1] + as[2] + as[3];
        float SS = ass[0] + ass[1] + ass[2] + ass[3];
        float m_ = S * (1.f / 768.f);
        float v = SS * (1.f / 768.f) - m_ * m_;
        v = fmaxf(v, 0.f);
        mu[row] = m_;
        rstd[row] = rsqrtf(v + 1e-5f);
    }
}

// ---------------- LN apply + transpose back + residual: y = LN(o2)^T + x ----------------
__global__ __launch_bounds__(256) void k_lnt(const float* __restrict__ o2,
                                             const float* __restrict__ mu,
                                             const float* __restrict__ rstd,
                                             const float* __restrict__ gamma,
                                             const float* __restrict__ beta,
                                             const float* __restrict__ x,
                                             float* __restrict__ y) {
    __shared__ float tile[64][65];
    const int b = blockIdx.z, hw0 = blockIdx.y * 64, cd0 = blockIdx.x * 64;
    const int tid = threadIdx.x;
#pragma unroll
    for (int i = 0; i < 16; i++) {
        int f = i * 256 + tid;
        int hwl = f >> 6, cdl = f & 63;
        int row = b * 1024 + hw0 + hwl;
        float v = o2[(size_t)row * 768 + cd0 + cdl];
        v = (v - mu[row]) * rstd[row] * gamma[cd0 + cdl] + beta[cd0 + cdl];
        tile[hwl][cdl] = v;
    }
    __syncthreads();
#pragma unroll
    for (int i = 0; i < 16; i++) {
        int f = i * 256 + tid;
        int cdl = f >> 6, hwl = f & 63;
        int cd = cd0 + cdl, c = cd >> 3, d = cd & 7;
        size_t addr = (size_t)((b * 96 + c) * 8 + d) * 1024 + hw0 + hwl;
        y[addr] = tile[hwl][cdl] + x[addr];
    }
}

// ---------------- depthwise 3x3x3 conv (x-layout), z = dw(y) + dw_b ----------------
__global__ __launch_bounds__(256) void k_dw(const float* __restrict__ y,
                                            const float* __restrict__ w,
                                            const float* __restrict__ bias,
                                            float* __restrict__ z) {
    int e = blockIdx.x * 256 + threadIdx.x;
    int hw = e & 1023;
    int rest = e >> 10;
    int d = rest & 7;
    int c = (rest >> 3) % 96;
    int h = hw >> 5, ww = hw & 31;
    float acc = bias[c];
    const float* wp = w + c * 27;
#pragma unroll
    for (int kd = 0; kd < 3; kd++) {
        int dd = d + kd - 1;
        if (dd < 0 || dd >= 8) continue;
#pragma unroll
        for (int kh = 0; kh < 3; kh++) {
            int hh = h + kh - 1;
            if ((unsigned)hh >= 32u) continue;
#pragma unroll
            for (int kw = 0; kw < 3; kw++) {
                int w2 = ww + kw - 1;
                if ((unsigned)w2 >= 32u) continue;
                acc += wp[kd * 9 + kh * 3 + kw] * y[e + (kd - 1) * 1024 + (kh - 1) * 32 + (kw - 1)];
            }
        }
    }
    z[e] = acc;
}

// ---------------- pointwise conv + final residual: out = y + pw(z) + pw_b ----------------
__global__ __launch_bounds__(256) void k_pw(const float* __restrict__ z,
                                            const float* __restrict__ yy,
                                            const float* __restrict__ w,
                                            const float* __restrict__ bias,
                                            float* __restrict__ out) {
    __shared__ float zr[96 * 32];
    __shared__ float yr[96 * 32];
    const int idx = blockIdx.x;
    const int h = idx & 31, d = (idx >> 5) & 7, b = idx >> 8;
    const int tid = threadIdx.x;
    const size_t base = ((size_t)b * 96 * 8 + d) * 1024 + h * 32;
#pragma unroll
    for (int i = 0; i < 12; i++) {
        int f = i * 256 + tid;
        int c = f >> 5, w2 = f & 31;
        size_t a = base + (size_t)c * 8192 + w2;
        zr[f] = z[a];
        yr[f] = yy[a];
    }
    __syncthreads();
#pragma unroll
    for (int i = 0; i < 12; i++) {
        int f = i * 256 + tid;
        int c = f >> 5, w2 = f & 31;
        float acc = yr[f] + bias[c];
        const float* wp = w + c * 96;
#pragma unroll 4
        for (int cc = 0; cc < 96; cc++) acc += wp[cc] * zr[cc * 32 + w2];
        out[base + (size_t)c * 8192 + w2] = acc;
    }
}

extern "C" void kernel_launch(void* const* d_in, const int* in_sizes, int n_in,
                              void* d_out, int out_size, void* d_ws, size_t ws_size,
                              hipStream_t stream) {
    (void)in_sizes; (void)n_in; (void)out_size; (void)ws_size;
    const float* x      = (const float*)d_in[0];
    const float* pos    = (const float*)d_in[1];
    const float* qkv_w  = (const float*)d_in[2];
    const float* proj_w = (const float*)d_in[3];
    const float* proj_b = (const float*)d_in[4];
    const float* temp   = (const float*)d_in[5];
    const float* ln_g   = (const float*)d_in[6];
    const float* ln_b   = (const float*)d_in[7];
    const float* dw_w   = (const float*)d_in[8];
    const float* dw_b   = (const float*)d_in[9];
    const float* pw_w   = (const float*)d_in[10];
    const float* pw_b   = (const float*)d_in[11];
    float* out = (float*)d_out;
    char* ws = (char*)d_ws;

    u16* t    = (u16*)(ws + 0);           // 12.58MB ; later aliased by z (with vT)
    u16* vT   = (u16*)(ws + 12582912);    // 12.58MB
    u16* q    = (u16*)(ws + 25165824);    // 12.58MB ; later aliased by o2 (with k)
    u16* kk   = (u16*)(ws + 37748736);    // 12.58MB
    u16* wqb  = (u16*)(ws + 50331648);    // qkv_w + proj_w bf16, 4.72MB
    float* cs   = (float*)(ws + 55050240);
    float* sqq  = (float*)(ws + 55074816);
    float* sqk  = (float*)(ws + 55099392);
    float* mu   = (float*)(ws + 55123968);
    float* rstd = (float*)(ws + 55156736);
    u16* wpb = wqb + 2304 * 768;
    u16* o   = t;          // attention output, aliases t (dead after QKV GEMM)
    float* o2 = (float*)q; // proj output fp32, aliases q+k (dead after attention)
    float* z  = (float*)t; // depthwise output, aliases t+vT (dead after proj GEMM)
    float* y  = out;       // residual-1 output lives in d_out

    k_tpos<<<dim3(12, 16, 8), 256, 0, stream>>>(x, pos, t);
    k_cvt<<<9216, 256, 0, stream>>>(qkv_w, proj_w, wqb);
    gemm_bt<0><<<1152, 256, 0, stream>>>(t, wqb, 8192, 2304, 768, q, kk, vT, nullptr, nullptr);
    hipMemsetAsync(sqq, 0, 49152, stream);
    k_sq<<<dim3(32, 8), 192, 0, stream>>>(q, kk, sqq, sqk);
    k_scale<<<32, 192, 0, stream>>>(sqq, sqk, temp, cs);
    k_attn<<<dim3(16, 32), 256, 0, stream>>>(q, kk, vT, cs, o);
    gemm_bt<1><<<384, 256, 0, stream>>>(o, wpb, 8192, 768, 768, nullptr, nullptr, nullptr, proj_b, o2);
    k_lnstats<<<8192, 256, 0, stream>>>(o2, mu, rstd);
    k_lnt<<<dim3(12, 16, 8), 256, 0, stream>>>(o2, mu, rstd, ln_g, ln_b, x, y);
    k_dw<<<24576, 256, 0, stream>>>(y, dw_w, dw_b, z);
    k_pw<<<2048, 256, 0, stream>>>(z, y, pw_w, pw_b, out);
}

// Round 2
// 411.913 us; speedup vs baseline: 1.1928x; 1.1928x over previous
//
#include <hip/hip_runtime.h>

typedef unsigned short u16;
typedef unsigned int u32;

typedef __attribute__((ext_vector_type(8))) short short8;
typedef __attribute__((ext_vector_type(4))) float floatx4;

__device__ __forceinline__ float bf2f(u16 u) { return __uint_as_float(((u32)u) << 16); }
__device__ __forceinline__ u16 f2bf(float f) {
    u32 x = __float_as_uint(f);
    x += 0x7fffu + ((x >> 16) & 1u);
    return (u16)(x >> 16);
}
__device__ __forceinline__ void gl_lds16(const void* g, void* l) {
    __builtin_amdgcn_global_load_lds((const __attribute__((address_space(1))) u32*)g,
                                     (__attribute__((address_space(3))) u32*)l, 16, 0, 0);
}

// ---------------- Kernel 1: x (B,C,D,H,W) -> t (B,HW,DIM) bf16, + pos ----------------
__global__ __launch_bounds__(256) void k_tpos(const float* __restrict__ x,
                                              const float* __restrict__ pos,
                                              u16* __restrict__ t) {
    __shared__ float tile[64][65];
    const int b = blockIdx.z, hw0 = blockIdx.y * 64, cd0 = blockIdx.x * 64;
    const int tid = threadIdx.x;
#pragma unroll
    for (int i = 0; i < 16; i++) {
        int f = i * 256 + tid;
        int cdl = f >> 6, hwl = f & 63;
        int cd = cd0 + cdl, c = cd >> 3, d = cd & 7;
        tile[cdl][hwl] = x[(size_t)(((b * 96 + c) * 8 + d)) * 1024 + hw0 + hwl];
    }
    __syncthreads();
#pragma unroll
    for (int i = 0; i < 16; i++) {
        int f = i * 256 + tid;
        int hwl = f >> 6, cdl = f & 63;
        float v = tile[cdl][hwl] + pos[(size_t)(hw0 + hwl) * 768 + cd0 + cdl];
        t[(size_t)(b * 1024 + hw0 + hwl) * 768 + cd0 + cdl] = f2bf(v);
    }
}

// ---------------- weight fp32 -> bf16 (qkv_w, proj_w, pw_w concatenated) ----------------
__global__ __launch_bounds__(256) void k_cvt(const float* __restrict__ wq,
                                             const float* __restrict__ wp,
                                             const float* __restrict__ wpw,
                                             u16* __restrict__ out) {
    int i = blockIdx.x * 256 + threadIdx.x;
    const int NQ = 2304 * 768;
    const int NP = NQ + 768 * 768;
    float v;
    if (i < NQ) v = wq[i];
    else if (i < NP) v = wp[i - NQ];
    else v = wpw[i - NP];
    out[i] = f2bf(v);
}

// ---------------- GEMM: C(M,N) = A(M,K) * Bw(N,K)^T, bf16 MFMA ----------------
// MODE 0: QKV epilogue -> q,k [b,h,n,dh] and v transposed [b,h,dh,n]
// MODE 1: proj epilogue -> Co fp32 row-major + bias
template <int MODE>
__global__ __launch_bounds__(256) void gemm_bt(const u16* __restrict__ A,
                                               const u16* __restrict__ Bw,
                                               int M, int N, int K,
                                               u16* __restrict__ qo, u16* __restrict__ ko,
                                               u16* __restrict__ vo,
                                               const float* __restrict__ bias,
                                               float* __restrict__ Co) {
    __shared__ __align__(16) u16 lA[128 * 32];
    __shared__ __align__(16) u16 lB[128 * 32];
    const int tid = threadIdx.x;
    const int lane = tid & 63;
    const int wv = tid >> 6;
    const int wr = wv >> 1, wc = wv & 1;
    const int ntiles = N >> 7;
    const int m0 = (blockIdx.x / ntiles) << 7;
    const int n0 = (blockIdx.x % ntiles) << 7;
    const int lr = lane & 15;
    const int lq = lane >> 4;
    const int koff = lq * 8;

    floatx4 acc[4][4];
#pragma unroll
    for (int i = 0; i < 4; i++)
#pragma unroll
        for (int j = 0; j < 4; j++) acc[i][j] = (floatx4){0.f, 0.f, 0.f, 0.f};

    for (int kt = 0; kt < K; kt += 32) {
        __syncthreads();
#pragma unroll
        for (int i = 0; i < 2; i++) {
            int ch = i * 256 + tid;
            int row = ch >> 2, kc = ch & 3;
            const u16* ga = A + (size_t)(m0 + row) * K + kt + kc * 8;
            gl_lds16(ga, (char*)lA + (i * 256 + (tid & ~63)) * 16);
            const u16* gb = Bw + (size_t)(n0 + row) * K + kt + kc * 8;
            gl_lds16(gb, (char*)lB + (i * 256 + (tid & ~63)) * 16);
        }
        __syncthreads();
        short8 af[4], bfr[4];
#pragma unroll
        for (int tt = 0; tt < 4; tt++) {
            af[tt] = *(const short8*)(lA + (wr * 64 + tt * 16 + lr) * 32 + koff);
            bfr[tt] = *(const short8*)(lB + (wc * 64 + tt * 16 + lr) * 32 + koff);
        }
#pragma unroll
        for (int mt = 0; mt < 4; mt++)
#pragma unroll
            for (int nt = 0; nt < 4; nt++)
                acc[mt][nt] = __builtin_amdgcn_mfma_f32_16x16x32_bf16(af[mt], bfr[nt], acc[mt][nt], 0, 0, 0);
    }

    if (MODE == 0) {
#pragma unroll
        for (int nt = 0; nt < 4; nt++) {
            int col = n0 + wc * 64 + nt * 16 + lr;
            int three = col / 768;
            int rem = col - three * 768;
            int h = rem / 192;
            int dh = rem - h * 192;
#pragma unroll
            for (int mt = 0; mt < 4; mt++) {
#pragma unroll
                for (int r = 0; r < 4; r++) {
                    int row = m0 + wr * 64 + mt * 16 + lq * 4 + r;
                    int b = row >> 10, n = row & 1023;
                    u16 val = f2bf(acc[mt][nt][r]);
                    size_t bh = (size_t)(b * 4 + h);
                    if (three == 0)
                        qo[(bh * 1024 + n) * 192 + dh] = val;
                    else if (three == 1)
                        ko[(bh * 1024 + n) * 192 + dh] = val;
                    else
                        vo[(bh * 192 + dh) * 1024 + n] = val;
                }
            }
        }
    } else {
#pragma unroll
        for (int nt = 0; nt < 4; nt++) {
            int col = n0 + wc * 64 + nt * 16 + lr;
            float bv = bias[col];
#pragma unroll
            for (int mt = 0; mt < 4; mt++) {
#pragma unroll
                for (int r = 0; r < 4; r++) {
                    int row = m0 + wr * 64 + mt * 16 + lq * 4 + r;
                    Co[(size_t)row * N + col] = acc[mt][nt][r] + bv;
                }
            }
        }
    }
}

// ---------------- column sum-of-squares over sequence (for l2norm over dim=-2) ----------------
__global__ void k_sq(const u16* __restrict__ q, const u16* __restrict__ k,
                     float* __restrict__ sqq, float* __restrict__ sqk) {
    int bh = blockIdx.x;
    int part = blockIdx.y;
    int dh = threadIdx.x;  // 192
    const u16* qp = q + ((size_t)bh * 1024 + part * 128) * 192 + dh;
    const u16* kp = k + ((size_t)bh * 1024 + part * 128) * 192 + dh;
    float aq = 0.f, ak = 0.f;
#pragma unroll 4
    for (int n = 0; n < 128; n++) {
        float a = bf2f(qp[(size_t)n * 192]);
        aq += a * a;
        float c2 = bf2f(kp[(size_t)n * 192]);
        ak += c2 * c2;
    }
    atomicAdd(&sqq[bh * 192 + dh], aq);
    atomicAdd(&sqk[bh * 192 + dh], ak);
}

__global__ void k_scale(const float* __restrict__ sqq, const float* __restrict__ sqk,
                        const float* __restrict__ temp, float* __restrict__ cs) {
    int bh = blockIdx.x;
    int dh = threadIdx.x;
    float rq = 1.f / fmaxf(sqrtf(sqq[bh * 192 + dh]), 1e-12f);
    float rk = 1.f / fmaxf(sqrtf(sqk[bh * 192 + dh]), 1e-12f);
    cs[bh * 192 + dh] = rq * rk * temp[bh & 3];
}

// ---------------- flash attention: one WG per (bh, 64-row q block) ----------------
__global__ __launch_bounds__(256) void k_attn(const u16* __restrict__ q,
                                              const u16* __restrict__ kmat,
                                              const u16* __restrict__ vT,
                                              const float* __restrict__ cs,
                                              u16* __restrict__ o) {
    __shared__ __align__(16) u16 lK[64 * 192];   // 24KB [krow][dh]
    __shared__ __align__(16) u16 lV[192 * 64];   // 24KB [dh][krow]
    __shared__ __align__(16) u16 lP[4 * 16 * 64];  // 8KB per-wave [qrow][krow]
    const int qb = blockIdx.x;
    const int bh = blockIdx.y;
    const int b = bh >> 2, h = bh & 3;
    const int tid = threadIdx.x;
    const int lane = tid & 63;
    const int wv = tid >> 6;
    const int lr = lane & 15;
    const int lq = lane >> 4;
    const int koff = lq * 8;

    const u16* qbase = q + (size_t)bh * 1024 * 192;
    const u16* kbase = kmat + (size_t)bh * 1024 * 192;
    const u16* vbase = vT + (size_t)bh * 192 * 1024;
    const float* cp = cs + bh * 192;

    // Q fragments in registers, scaled by combined norm/temperature factor
    const int qrow = qb * 64 + wv * 16 + lr;
    const u16* qp = qbase + (size_t)qrow * 192;
    short8 qf[6];
#pragma unroll
    for (int ks = 0; ks < 6; ks++) {
        short8 raw = *(const short8*)(qp + ks * 32 + koff);
        short8 sc;
#pragma unroll
        for (int j = 0; j < 8; j++) {
            float f = bf2f((u16)raw[j]) * cp[ks * 32 + koff + j];
            sc[j] = (short)f2bf(f);
        }
        qf[ks] = sc;
    }

    float m_r[4], l_r[4];
    floatx4 oacc[12];
#pragma unroll
    for (int r = 0; r < 4; r++) { m_r[r] = -1e30f; l_r[r] = 0.f; }
#pragma unroll
    for (int vt = 0; vt < 12; vt++) oacc[vt] = (floatx4){0.f, 0.f, 0.f, 0.f};

    for (int kb = 0; kb < 16; kb++) {
        __syncthreads();
        // stage K block [64][192] and V^T block [192][64]
#pragma unroll
        for (int i = 0; i < 6; i++) {
            int ch = i * 256 + tid;
            int r = ch / 24, cc = ch - r * 24;
            const u16* gk = kbase + (size_t)(kb * 64 + r) * 192 + cc * 8;
            gl_lds16(gk, (char*)lK + (i * 256 + (tid & ~63)) * 16);
            int dh2 = ch >> 3, c2 = ch & 7;
            const u16* gv = vbase + (size_t)dh2 * 1024 + kb * 64 + c2 * 8;
            gl_lds16(gv, (char*)lV + (i * 256 + (tid & ~63)) * 16);
        }
        __syncthreads();

        // S = Qs * K^T : 4 n-tiles of 16
        floatx4 s[4];
#pragma unroll
        for (int nt = 0; nt < 4; nt++) s[nt] = (floatx4){0.f, 0.f, 0.f, 0.f};
#pragma unroll
        for (int ks = 0; ks < 6; ks++) {
#pragma unroll
            for (int nt = 0; nt < 4; nt++) {
                short8 kf = *(const short8*)(lK + (nt * 16 + lr) * 192 + ks * 32 + koff);
                s[nt] = __builtin_amdgcn_mfma_f32_16x16x32_bf16(qf[ks], kf, s[nt], 0, 0, 0);
            }
        }

        // online softmax (rows = lq*4 + r, consistent across the 16 lanes of each quad)
        float rmax[4];
#pragma unroll
        for (int r = 0; r < 4; r++)
            rmax[r] = fmaxf(fmaxf(s[0][r], s[1][r]), fmaxf(s[2][r], s[3][r]));
#pragma unroll
        for (int m = 1; m < 16; m <<= 1)
#pragma unroll
            for (int r = 0; r < 4; r++) rmax[r] = fmaxf(rmax[r], __shfl_xor(rmax[r], m));
        float alpha[4];
#pragma unroll
        for (int r = 0; r < 4; r++) {
            float mn = fmaxf(m_r[r], rmax[r]);
            alpha[r] = __expf(m_r[r] - mn);
            m_r[r] = mn;
        }
        float rsum[4] = {0.f, 0.f, 0.f, 0.f};
#pragma unroll
        for (int nt = 0; nt < 4; nt++)
#pragma unroll
            for (int r = 0; r < 4; r++) {
                float p = __expf(s[nt][r] - m_r[r]);
                s[nt][r] = p;
                rsum[r] += p;
            }
#pragma unroll
        for (int m = 1; m < 16; m <<= 1)
#pragma unroll
            for (int r = 0; r < 4; r++) rsum[r] += __shfl_xor(rsum[r], m);
#pragma unroll
        for (int r = 0; r < 4; r++) l_r[r] = l_r[r] * alpha[r] + rsum[r];
#pragma unroll
        for (int vt = 0; vt < 12; vt++)
#pragma unroll
            for (int r = 0; r < 4; r++) oacc[vt][r] *= alpha[r];

        // P -> per-wave LDS (C-layout -> A-layout transform)
        u16* lp = lP + wv * (16 * 64);
#pragma unroll
        for (int nt = 0; nt < 4; nt++)
#pragma unroll
            for (int r = 0; r < 4; r++)
                lp[(lq * 4 + r) * 64 + nt * 16 + lr] = f2bf(s[nt][r]);

        // O += P * V
#pragma unroll
        for (int ks2 = 0; ks2 < 2; ks2++) {
            short8 pf = *(const short8*)(lp + lr * 64 + ks2 * 32 + koff);
#pragma unroll
            for (int vt = 0; vt < 12; vt++) {
                short8 vf = *(const short8*)(lV + (vt * 16 + lr) * 64 + ks2 * 32 + koff);
                oacc[vt] = __builtin_amdgcn_mfma_f32_16x16x32_bf16(pf, vf, oacc[vt], 0, 0, 0);
            }
        }
    }

    // epilogue: divide by l, write to o (B,HW,DIM) bf16
    float inv[4];
#pragma unroll
    for (int r = 0; r < 4; r++) inv[r] = 1.f / l_r[r];
#pragma unroll
    for (int vt = 0; vt < 12; vt++) {
        int dh = vt * 16 + lr;
#pragma unroll
        for (int r = 0; r < 4; r++) {
            int row = qb * 64 + wv * 16 + lq * 4 + r;
            o[(size_t)(b * 1024 + row) * 768 + h * 192 + dh] = f2bf(oacc[vt][r] * inv[r]);
        }
    }
}

// ---------------- LN stats per row ----------------
__global__ __launch_bounds__(256) void k_lnstats(const float* __restrict__ o2,
                                                 float* __restrict__ mu,
                                                 float* __restrict__ rstd) {
    int row = blockIdx.x;
    int tid = threadIdx.x;
    const float* p = o2 + (size_t)row * 768;
    float s = 0.f, ss = 0.f;
    for (int i = tid; i < 768; i += 256) {
        float v = p[i];
        s += v;
        ss += v * v;
    }
#pragma unroll
    for (int m = 32; m >= 1; m >>= 1) {
        s += __shfl_xor(s, m);
        ss += __shfl_xor(ss, m);
    }
    __shared__ float as[4], ass[4];
    if ((tid & 63) == 0) {
        as[tid >> 6] = s;
        ass[tid >> 6] = ss;
    }
    __syncthreads();
    if (tid == 0) {
        float S = as[0] + as[1] + as[2] + as[3];
        float SS = ass[0] + ass[1] + ass[2] + ass[3];
        float m_ = S * (1.f / 768.f);
        float v = SS * (1.f / 768.f) - m_ * m_;
        v = fmaxf(v, 0.f);
        mu[row] = m_;
        rstd[row] = rsqrtf(v + 1e-5f);
    }
}

// ---------------- LN apply + transpose back + residual: y = LN(o2)^T + x ----------------
__global__ __launch_bounds__(256) void k_lnt(const float* __restrict__ o2,
                                             const float* __restrict__ mu,
                                             const float* __restrict__ rstd,
                                             const float* __restrict__ gamma,
                                             const float* __restrict__ beta,
                                             const float* __restrict__ x,
                                             float* __restrict__ y) {
    __shared__ float tile[64][65];
    const int b = blockIdx.z, hw0 = blockIdx.y * 64, cd0 = blockIdx.x * 64;
    const int tid = threadIdx.x;
#pragma unroll
    for (int i = 0; i < 16; i++) {
        int f = i * 256 + tid;
        int hwl = f >> 6, cdl = f & 63;
        int row = b * 1024 + hw0 + hwl;
        float v = o2[(size_t)row * 768 + cd0 + cdl];
        v = (v - mu[row]) * rstd[row] * gamma[cd0 + cdl] + beta[cd0 + cdl];
        tile[hwl][cdl] = v;
    }
    __syncthreads();
#pragma unroll
    for (int i = 0; i < 16; i++) {
        int f = i * 256 + tid;
        int cdl = f >> 6, hwl = f & 63;
        int cd = cd0 + cdl, c = cd >> 3, d = cd & 7;
        size_t addr = (size_t)((b * 96 + c) * 8 + d) * 1024 + hw0 + hwl;
        y[addr] = tile[hwl][cdl] + x[addr];
    }
}

// ---------------- depthwise 3x3x3 conv (x-layout), z = dw(y) + dw_b ----------------
__global__ __launch_bounds__(256) void k_dw(const float* __restrict__ y,
                                            const float* __restrict__ w,
                                            const float* __restrict__ bias,
                                            float* __restrict__ z) {
    int e = blockIdx.x * 256 + threadIdx.x;
    int hw = e & 1023;
    int rest = e >> 10;
    int d = rest & 7;
    int c = (rest >> 3) % 96;
    int h = hw >> 5, ww = hw & 31;
    float acc = bias[c];
    const float* wp = w + c * 27;
#pragma unroll
    for (int kd = 0; kd < 3; kd++) {
        int dd = d + kd - 1;
        if (dd < 0 || dd >= 8) continue;
#pragma unroll
        for (int kh = 0; kh < 3; kh++) {
            int hh = h + kh - 1;
            if ((unsigned)hh >= 32u) continue;
#pragma unroll
            for (int kw = 0; kw < 3; kw++) {
                int w2 = ww + kw - 1;
                if ((unsigned)w2 >= 32u) continue;
                acc += wp[kd * 9 + kh * 3 + kw] * y[e + (kd - 1) * 1024 + (kh - 1) * 32 + (kw - 1)];
            }
        }
    }
    z[e] = acc;
}

// ---------------- pointwise conv via MFMA: out = y + pw_b + W(96x96) * Z(96 x pos) ----------------
// One block per (b, d, 128-pos chunk). Z staged transposed to LDS bf16 [pos][cc].
__global__ __launch_bounds__(256) void k_pw(const float* __restrict__ z,
                                            const u16* __restrict__ wbf,   // bf16 96x96 [c][cc]
                                            const float* __restrict__ bias,
                                            float* __restrict__ out) {     // also y input (in-place)
    __shared__ __align__(16) u16 lZ[128 * 104];  // [pos][cc], stride 104
    __shared__ __align__(16) u16 lW[96 * 104];   // [c][cc], stride 104
    const int tid = threadIdx.x;
    const int lane = tid & 63;
    const int wv = tid >> 6;
    const int lr = lane & 15;
    const int lq = lane >> 4;
    const int koff = lq * 8;

    const int idx = blockIdx.x;
    const int q = idx & 7;          // pos chunk
    const int bd = idx >> 3;
    const int b = bd >> 3, d = bd & 7;
    const int pos0 = q * 128;

    // stage W -> LDS (rows of 96, stride 104)
    for (int i = tid; i < 96 * 96; i += 256) {
        int row = i / 96, col = i - row * 96;
        lW[row * 104 + col] = wbf[i];
    }

    // stage Z transposed: thread covers pos = tid&127, cc = (tid>>7)*48 .. +47
    {
        const int pos = tid & 127;
        const int cc0 = (tid >> 7) * 48;
        const size_t gbase = ((size_t)b * 96 * 8 + d) * 1024 + pos0 + pos;
#pragma unroll
        for (int g = 0; g < 6; g++) {
            short8 v;
#pragma unroll
            for (int j = 0; j < 8; j++) {
                int cc = cc0 + g * 8 + j;
                v[j] = (short)f2bf(z[gbase + (size_t)cc * 8192]);
            }
            *(short8*)(lZ + pos * 104 + cc0 + g * 8) = v;
        }
    }
    __syncthreads();

    // MFMA: 6 m-tiles (c), 2 n-tiles per wave (pos), K=96 in 3 steps
    floatx4 acc[6][2];
#pragma unroll
    for (int m = 0; m < 6; m++)
#pragma unroll
        for (int nt = 0; nt < 2; nt++) acc[m][nt] = (floatx4){0.f, 0.f, 0.f, 0.f};

#pragma unroll
    for (int ks = 0; ks < 3; ks++) {
        short8 bfrg[2];
#pragma unroll
        for (int nt = 0; nt < 2; nt++)
            bfrg[nt] = *(const short8*)(lZ + (wv * 32 + nt * 16 + lr) * 104 + ks * 32 + koff);
#pragma unroll
        for (int m = 0; m < 6; m++) {
            short8 afr = *(const short8*)(lW + (m * 16 + lr) * 104 + ks * 32 + koff);
#pragma unroll
            for (int nt = 0; nt < 2; nt++)
                acc[m][nt] = __builtin_amdgcn_mfma_f32_16x16x32_bf16(afr, bfrg[nt], acc[m][nt], 0, 0, 0);
        }
    }

    // epilogue: out = y(out) + bias[c] + acc   (each addr read+written by same thread)
#pragma unroll
    for (int m = 0; m < 6; m++) {
#pragma unroll
        for (int r = 0; r < 4; r++) {
            int c = m * 16 + lq * 4 + r;
            float bv = bias[c];
            size_t rowbase = ((size_t)(b * 96 + c) * 8 + d) * 1024 + pos0;
#pragma unroll
            for (int nt = 0; nt < 2; nt++) {
                int pos = wv * 32 + nt * 16 + lr;
                size_t a = rowbase + pos;
                out[a] = out[a] + bv + acc[m][nt][r];
            }
        }
    }
}

extern "C" void kernel_launch(void* const* d_in, const int* in_sizes, int n_in,
                              void* d_out, int out_size, void* d_ws, size_t ws_size,
                              hipStream_t stream) {
    (void)in_sizes; (void)n_in; (void)out_size; (void)ws_size;
    const float* x      = (const float*)d_in[0];
    const float* pos    = (const float*)d_in[1];
    const float* qkv_w  = (const float*)d_in[2];
    const float* proj_w = (const float*)d_in[3];
    const float* proj_b = (const float*)d_in[4];
    const float* temp   = (const float*)d_in[5];
    const float* ln_g   = (const float*)d_in[6];
    const float* ln_b   = (const float*)d_in[7];
    const float* dw_w   = (const float*)d_in[8];
    const float* dw_b   = (const float*)d_in[9];
    const float* pw_w   = (const float*)d_in[10];
    const float* pw_b   = (const float*)d_in[11];
    float* out = (float*)d_out;
    char* ws = (char*)d_ws;

    u16* t    = (u16*)(ws + 0);           // 12.58MB ; later aliased by z (with vT)
    u16* vT   = (u16*)(ws + 12582912);    // 12.58MB
    u16* q    = (u16*)(ws + 25165824);    // 12.58MB ; later aliased by o2 (with k)
    u16* kk   = (u16*)(ws + 37748736);    // 12.58MB
    u16* wqb  = (u16*)(ws + 50331648);    // qkv_w + proj_w + pw_w bf16, ~4.74MB
    float* cs   = (float*)(ws + 55150592);
    float* sqq  = (float*)(ws + 55175168);
    float* sqk  = (float*)(ws + 55199744);
    float* mu   = (float*)(ws + 55224320);
    float* rstd = (float*)(ws + 55257088);
    u16* wpb  = wqb + 2304 * 768;
    u16* wpwb = wqb + 2304 * 768 + 768 * 768;
    u16* o   = t;          // attention output, aliases t (dead after QKV GEMM)
    float* o2 = (float*)q; // proj output fp32, aliases q+k (dead after attention)
    float* z  = (float*)t; // depthwise output, aliases t+vT (dead after proj GEMM)
    float* y  = out;       // residual-1 output lives in d_out

    k_tpos<<<dim3(12, 16, 8), 256, 0, stream>>>(x, pos, t);
    k_cvt<<<9252, 256, 0, stream>>>(qkv_w, proj_w, pw_w, wqb);
    gemm_bt<0><<<1152, 256, 0, stream>>>(t, wqb, 8192, 2304, 768, q, kk, vT, nullptr, nullptr);
    hipMemsetAsync(sqq, 0, 49152, stream);
    k_sq<<<dim3(32, 8), 192, 0, stream>>>(q, kk, sqq, sqk);
    k_scale<<<32, 192, 0, stream>>>(sqq, sqk, temp, cs);
    k_attn<<<dim3(16, 32), 256, 0, stream>>>(q, kk, vT, cs, o);
    gemm_bt<1><<<384, 256, 0, stream>>>(o, wpb, 8192, 768, 768, nullptr, nullptr, nullptr, proj_b, o2);
    k_lnstats<<<8192, 256, 0, stream>>>(o2, mu, rstd);
    k_lnt<<<dim3(12, 16, 8), 256, 0, stream>>>(o2, mu, rstd, ln_g, ln_b, x, y);
    k_dw<<<24576, 256, 0, stream>>>(y, dw_w, dw_b, z);
    k_pw<<<512, 256, 0, stream>>>(z, wpwb, pw_b, out);
}